// Round 1
// baseline (125.290 us; speedup 1.0000x reference)
//
#include <hip/hip_runtime.h>
#include <math.h>

#define D_DIM 100000
#define W_DIM 128
#define BATCH 4096

// One wave (64 lanes) per batch element.
// Lane l handles embedding dims w=l and w=l+64.
__global__ __launch_bounds__(256) void sgns_kernel(
    const int* __restrict__ idx1,
    const int* __restrict__ idx2,
    const float* __restrict__ W1,
    const float* __restrict__ b1,
    const float* __restrict__ W2,
    const float* __restrict__ b2,
    float* __restrict__ out)
{
    const int gtid = blockIdx.x * blockDim.x + threadIdx.x;
    const int wave = gtid >> 6;        // batch element
    const int lane = gtid & 63;
    if (wave >= BATCH) return;

    const int i1 = idx1[wave];
    const int i2 = idx2[wave];

    const int w0 = lane;
    const int w1 = lane + 64;

    // 4 independent scattered loads (each on its own cacheline; stride 400KB
    // along the column, so no coalescing is possible in this layout).
    const float a0 = W1[w0 * D_DIM + i1];
    const float a1 = W1[w1 * D_DIM + i1];
    const float c0 = W2[w0 * D_DIM + i2];
    const float c1 = W2[w1 * D_DIM + i2];

    // Bias vectors are tiny (128 floats) -> L1/L2 resident.
    const float p0 = a0 + b1[w0];
    const float p1 = a1 + b1[w1];
    const float q0 = c0 + b2[w0];
    const float q1 = c1 + b2[w1];

    float v = p0 * q0 + p1 * q1;

    // Wave-64 butterfly reduction.
    #pragma unroll
    for (int off = 32; off > 0; off >>= 1)
        v += __shfl_down(v, off, 64);

    if (lane == 0) {
        const float s = 1.0f / (1.0f + expf(-v));
        out[wave * 2 + 0] = 1.0f - s;
        out[wave * 2 + 1] = s;
    }
}

extern "C" void kernel_launch(void* const* d_in, const int* in_sizes, int n_in,
                              void* d_out, int out_size, void* d_ws, size_t ws_size,
                              hipStream_t stream)
{
    const int*   idx1 = (const int*)  d_in[0];
    const int*   idx2 = (const int*)  d_in[1];
    const float* W1   = (const float*)d_in[2];
    const float* b1   = (const float*)d_in[3];
    const float* W2   = (const float*)d_in[4];
    const float* b2   = (const float*)d_in[5];
    float* out = (float*)d_out;

    const int threads = 256;                       // 4 waves/block
    const int blocks  = (BATCH * 64) / threads;    // 1024 blocks
    sgns_kernel<<<blocks, threads, 0, stream>>>(idx1, idx2, W1, b1, W2, b2, out);
}